// Round 12
// baseline (434.502 us; speedup 1.0000x reference)
//
#include <hip/hip_runtime.h>
#include <hip/hip_bf16.h>
#include <math.h>

#define T_TOK 2048
#define H_DIM 2048
#define E_EXP 16
#define I_DIM 512
#define TWO_I 1024
#define ROUTED_SCALE 1.5f
#define SWIGLU_LIMIT 7.0f

#define BM 128            // gemm1 tile rows / A_tok padding
#define KC 32             // gemm1 K-chunk
#define KC2 64            // gemm2 K-chunk
#define MAX_TILES 48      // 128-row tiles
#define SLOTS 6144
#define NSPL 4            // gemm1 K-split
#define JCAP 512          // per-XCD job capacity

typedef __attribute__((ext_vector_type(8))) short bf16x8;
typedef __attribute__((ext_vector_type(4))) float f32x4;
typedef unsigned short u16;

__device__ inline u16 f2bf(float f) {
    return __builtin_bit_cast(u16, __float2bfloat16(f));
}
__device__ inline float bf2f(u16 h) {
    unsigned int u = ((unsigned int)h) << 16;
    return __builtin_bit_cast(float, u);
}
__device__ inline ushort4 pack4(float4 a) {
    ushort4 v;
    v.x = f2bf(a.x); v.y = f2bf(a.y); v.z = f2bf(a.z); v.w = f2bf(a.w);
    return v;
}
__device__ inline bf16x8 cvt8(float4 a, float4 b) {
    bf16x8 v;
    v[0] = (short)f2bf(a.x); v[1] = (short)f2bf(a.y);
    v[2] = (short)f2bf(a.z); v[3] = (short)f2bf(a.w);
    v[4] = (short)f2bf(b.x); v[5] = (short)f2bf(b.y);
    v[6] = (short)f2bf(b.z); v[7] = (short)f2bf(b.w);
    return v;
}

// async 16B/lane global->LDS DMA
__device__ inline void gload16(const u16* g, u16* l) {
    __builtin_amdgcn_global_load_lds(
        (const __attribute__((address_space(1))) void*)(g),
        (__attribute__((address_space(3))) void*)(l), 16, 0, 0);
}
#define SCHED0() __builtin_amdgcn_sched_barrier(0)

// swizzled ushort index for 64-elem bf16 rows
#define SWZ(row, k) ((row) * 64 + ((k) ^ (((row) & 7) << 3)))

// ---------------- router: TWO waves per token (H-split) ----------------
__global__ __launch_bounds__(256) void router_kernel(
    const float* __restrict__ hs, const float* __restrict__ gw,
    const float* __restrict__ bias, int* cnt, int* tok_list, float* w_list,
    u16* __restrict__ hs_bf)
{
    int w = threadIdx.x >> 6;
    int lane = threadIdx.x & 63;
    int t = blockIdx.x * 2 + (w >> 1);
    int kh = w & 1;
    const float* x = hs + (size_t)t * H_DIM + kh * 1024;
    const float* gwb = gw + kh * 1024;
    u16* hb = hs_bf + (size_t)t * H_DIM + kh * 1024;

    float acc[E_EXP];
#pragma unroll
    for (int e = 0; e < E_EXP; ++e) acc[e] = 0.f;

#pragma unroll
    for (int c = 0; c < 4; ++c) {
        int col = c * 256 + lane * 4;
        float4 xv = *(const float4*)(x + col);
        *(ushort4*)(hb + col) = pack4(xv);
#pragma unroll
        for (int e = 0; e < E_EXP; ++e) {
            float4 gv = *(const float4*)(gwb + (size_t)e * H_DIM + col);
            acc[e] = fmaf(xv.x, gv.x, acc[e]);
            acc[e] = fmaf(xv.y, gv.y, acc[e]);
            acc[e] = fmaf(xv.z, gv.z, acc[e]);
            acc[e] = fmaf(xv.w, gv.w, acc[e]);
        }
    }
#pragma unroll
    for (int e = 0; e < E_EXP; ++e) {
        for (int m = 32; m >= 1; m >>= 1)
            acc[e] += __shfl_xor(acc[e], m, 64);
    }
    __shared__ float part[4][E_EXP];
    if (lane == 0) {
#pragma unroll
        for (int e = 0; e < E_EXP; ++e) part[w][e] = acc[e];
    }
    __syncthreads();
    if (kh == 0 && lane == 0) {
        float sc[E_EXP], bsc[E_EXP];
#pragma unroll
        for (int e = 0; e < E_EXP; ++e) {
            float s = part[w][e] + part[w + 1][e];
            sc[e] = 1.f / (1.f + expf(-s));
            bsc[e] = sc[e] + bias[e];
        }
        int e0 = 0; float b0 = bsc[0];
#pragma unroll
        for (int e = 1; e < E_EXP; ++e) if (bsc[e] > b0) { b0 = bsc[e]; e0 = e; }
        int e1 = -1; float b1 = -1e30f;
#pragma unroll
        for (int e = 0; e < E_EXP; ++e) {
            if (e == e0) continue;
            if (bsc[e] > b1) { b1 = bsc[e]; e1 = e; }
        }
        float s0 = sc[e0], s1 = sc[e1];
        float inv = ROUTED_SCALE / (s0 + s1);
        int p0 = atomicAdd(&cnt[e0], 1);
        tok_list[e0 * T_TOK + p0] = t;
        w_list[e0 * T_TOK + p0] = s0 * inv;
        int p1 = atomicAdd(&cnt[e1], 1);
        tok_list[e1 * T_TOK + p1] = t;
        w_list[e1 * T_TOK + p1] = s1 * inv;
    }
}

// ---------------- fused: compaction + tiles + XCD-pinned job lists ----------------
// jobs1[xcd*JCAP + i] = tile*32 + y*4 + kspl   (gemm1; xcd = (e*4+kspl)&7)
// jobs2[xcd*JCAP + i] = tile2*32 + y           (gemm2; xcd = (e+y)&7; tile2 = 64-row subtile)
__global__ void scatter_build(const int* __restrict__ cnt,
    const int* __restrict__ tok_list, const float* __restrict__ w_list,
    int* A_tok, float* A_w, int* tile_e, int* tile_r0, int* n_slots,
    int* jobs1, int* jobs2)
{
    int c[E_EXP], offs[E_EXP + 1];
    offs[0] = 0;
#pragma unroll
    for (int e = 0; e < E_EXP; ++e) {
        c[e] = cnt[e];
        offs[e + 1] = offs[e] + ((c[e] + BM - 1) & ~(BM - 1));
    }
    int idx = blockIdx.x * 256 + threadIdx.x;
    int e = idx >> 11;
    int pos = idx & (T_TOK - 1);
    int ce = c[e];
    int pe = (ce + BM - 1) & ~(BM - 1);
    if (pos < ce) {
        A_tok[offs[e] + pos] = tok_list[idx];
        A_w[offs[e] + pos] = w_list[idx];
    } else if (pos < pe) {
        A_tok[offs[e] + pos] = -1;
        A_w[offs[e] + pos] = 0.f;
    }
    if (idx == 0) {
        int nt = 0;
        int c1[8], c2[8];
#pragma unroll
        for (int x = 0; x < 8; ++x) { c1[x] = 0; c2[x] = 0; }
        for (int ee = 0; ee < E_EXP; ++ee) {
            int ntile = (c[ee] + BM - 1) >> 7;
            for (int j = 0; j < ntile; ++j) {
                int t = nt;
                tile_e[t] = ee;
                tile_r0[t] = offs[ee] + j * BM;
                // gemm1 jobs: K-split x4, y x8
                for (int kspl = 0; kspl < NSPL; ++kspl) {
                    int x = (ee * 4 + kspl) & 7;
                    for (int y = 0; y < 8; ++y)
                        jobs1[x * JCAP + c1[x]++] = t * 32 + y * 4 + kspl;
                }
                // gemm2 jobs: two 64-row subtiles, y x32
                for (int s = 0; s < 2; ++s) {
                    int t2 = t * 2 + s;
                    for (int y = 0; y < 32; ++y) {
                        int x = (ee + y) & 7;
                        jobs2[x * JCAP + c2[x]++] = t2 * 32 + y;
                    }
                }
                ++nt;
            }
        }
        for (; nt < MAX_TILES; ++nt) tile_e[nt] = -1;
        *n_slots = offs[E_EXP];
    }
}

// ---------------- GEMM1 (K-split x4, XCD-pinned): partial G/U -> gu_part bf16 ----------------
__global__ __launch_bounds__(256, 3) void gemm1_gu(
    const u16* __restrict__ hs_bf, const float* __restrict__ w13,
    const int* __restrict__ A_tok, const int* __restrict__ tile_e,
    const int* __restrict__ tile_r0, const int* __restrict__ jobs1,
    u16* __restrict__ gu_part)
{
    int b = blockIdx.x;
    int job = jobs1[(b & 7) * JCAP + (b >> 3)];
    if (job < 0) return;
    int kspl = job & 3;
    int y = (job >> 2) & 7;
    int tile = job >> 5;
    int e = tile_e[tile];
    int row0 = tile_r0[tile];
    int i0 = y * 64;
    int k0base = kspl * (H_DIM / NSPL);     // 512-wide K slice
    int tid = threadIdx.x;

    __shared__ u16 Xs[2][4096];   // 128 x 32 bf16
    __shared__ u16 Gs[2][2048];   // 64 x 32 bf16
    __shared__ u16 Us[2][2048];

    const int l = tid & 63, w = tid >> 6;

    const u16* sX[2]; int dX[2];
#pragma unroll
    for (int j = 0; j < 2; ++j) {
        int row = w * 32 + j * 16 + (l >> 2);
        int tk = A_tok[row0 + row]; if (tk < 0) tk = 0;
        int sg = (l & 3) ^ ((l >> 3) & 3);
        sX[j] = hs_bf + (size_t)tk * H_DIM + k0base + sg * 8;
        dX[j] = (w * 32 + j * 16) * 32;
    }
#define X_STAGE(bb, t) do { int ko = (t) * KC; \
    gload16(sX[0] + ko, &Xs[bb][dX[0]]); gload16(sX[1] + ko, &Xs[bb][dX[1]]); } while (0)

    const int wr = tid >> 2;
    const int wg = tid & 3;
    const int wsk = (wg ^ ((wr >> 1) & 3)) * 8;
    const float* gsrc = w13 + ((size_t)e * TWO_I + i0 + wr) * H_DIM + k0base + wsk;
    const float* usrc = gsrc + (size_t)I_DIM * H_DIM;
    const int wdst = wr * 32 + wg * 8;

    float4 gA, gB, uA, uB;
#define W_LOAD(t) do { int ko = (t) * KC; \
    gA = *(const float4*)(gsrc + ko); gB = *(const float4*)(gsrc + ko + 4); \
    uA = *(const float4*)(usrc + ko); uB = *(const float4*)(usrc + ko + 4); } while (0)
#define W_WRITE(bb) do { \
    *(bf16x8*)&Gs[bb][wdst] = cvt8(gA, gB); \
    *(bf16x8*)&Us[bb][wdst] = cvt8(uA, uB); } while (0)

    const int wm = w >> 1, wn = w & 1;
    const int lr = l & 15, lg = l >> 4;
    const int swz = (lg ^ ((lr >> 1) & 3)) * 8;
    int ix[4], ib[2];
#pragma unroll
    for (int m = 0; m < 4; ++m) ix[m] = (wm * 64 + m * 16 + lr) * 32 + swz;
#pragma unroll
    for (int n = 0; n < 2; ++n) ib[n] = (wn * 32 + n * 16 + lr) * 32 + swz;

    const f32x4 Z4 = {0.f, 0.f, 0.f, 0.f};
    f32x4 aG[4][2], aU[4][2];
#pragma unroll
    for (int m = 0; m < 4; ++m)
#pragma unroll
        for (int n = 0; n < 2; ++n) { aG[m][n] = Z4; aU[m][n] = Z4; }

    W_LOAD(0);
    X_STAGE(0, 0);
    W_WRITE(0);
    __syncthreads();
    int cur = 0;
    const int NT = (H_DIM / NSPL) / KC;     // 16
    for (int t = 0; t < NT; ++t) {
        const bool more = (t + 1 < NT);
        if (more) {
            X_STAGE(cur ^ 1, t + 1);
            W_LOAD(t + 1);
            SCHED0();
        }
        {
            bf16x8 a0 = *(const bf16x8*)&Xs[cur][ix[0]];
            bf16x8 a1 = *(const bf16x8*)&Xs[cur][ix[1]];
            bf16x8 a2 = *(const bf16x8*)&Xs[cur][ix[2]];
            bf16x8 a3 = *(const bf16x8*)&Xs[cur][ix[3]];
            bf16x8 g0 = *(const bf16x8*)&Gs[cur][ib[0]];
            bf16x8 g1 = *(const bf16x8*)&Gs[cur][ib[1]];
            bf16x8 u0 = *(const bf16x8*)&Us[cur][ib[0]];
            bf16x8 u1 = *(const bf16x8*)&Us[cur][ib[1]];
            aG[0][0] = __builtin_amdgcn_mfma_f32_16x16x32_bf16(a0, g0, aG[0][0], 0, 0, 0);
            aG[0][1] = __builtin_amdgcn_mfma_f32_16x16x32_bf16(a0, g1, aG[0][1], 0, 0, 0);
            aG[1][0] = __builtin_amdgcn_mfma_f32_16x16x32_bf16(a1, g0, aG[1][0], 0, 0, 0);
            aG[1][1] = __builtin_amdgcn_mfma_f32_16x16x32_bf16(a1, g1, aG[1][1], 0, 0, 0);
            aG[2][0] = __builtin_amdgcn_mfma_f32_16x16x32_bf16(a2, g0, aG[2][0], 0, 0, 0);
            aG[2][1] = __builtin_amdgcn_mfma_f32_16x16x32_bf16(a2, g1, aG[2][1], 0, 0, 0);
            aG[3][0] = __builtin_amdgcn_mfma_f32_16x16x32_bf16(a3, g0, aG[3][0], 0, 0, 0);
            aG[3][1] = __builtin_amdgcn_mfma_f32_16x16x32_bf16(a3, g1, aG[3][1], 0, 0, 0);
            aU[0][0] = __builtin_amdgcn_mfma_f32_16x16x32_bf16(a0, u0, aU[0][0], 0, 0, 0);
            aU[0][1] = __builtin_amdgcn_mfma_f32_16x16x32_bf16(a0, u1, aU[0][1], 0, 0, 0);
            aU[1][0] = __builtin_amdgcn_mfma_f32_16x16x32_bf16(a1, u0, aU[1][0], 0, 0, 0);
            aU[1][1] = __builtin_amdgcn_mfma_f32_16x16x32_bf16(a1, u1, aU[1][1], 0, 0, 0);
            aU[2][0] = __builtin_amdgcn_mfma_f32_16x16x32_bf16(a2, u0, aU[2][0], 0, 0, 0);
            aU[2][1] = __builtin_amdgcn_mfma_f32_16x16x32_bf16(a2, u1, aU[2][1], 0, 0, 0);
            aU[3][0] = __builtin_amdgcn_mfma_f32_16x16x32_bf16(a3, u0, aU[3][0], 0, 0, 0);
            aU[3][1] = __builtin_amdgcn_mfma_f32_16x16x32_bf16(a3, u1, aU[3][1], 0, 0, 0);
        }
        if (more) W_WRITE(cur ^ 1);
        __syncthreads();
        cur ^= 1;
    }
#undef X_STAGE
#undef W_LOAD
#undef W_WRITE

    // bf16 partial sums: [kspl][slot][1024]
    u16* gp = gu_part + (size_t)kspl * SLOTS * TWO_I;
#pragma unroll
    for (int m = 0; m < 4; ++m)
#pragma unroll
        for (int n = 0; n < 2; ++n) {
            int col = i0 + wn * 32 + n * 16 + lr;
            int sbase = row0 + wm * 64 + m * 16 + lg * 4;
#pragma unroll
            for (int q = 0; q < 4; ++q) {
                gp[(size_t)(sbase + q) * TWO_I + col]         = f2bf(aG[m][n][q]);
                gp[(size_t)(sbase + q) * TWO_I + I_DIM + col] = f2bf(aU[m][n][q]);
            }
        }
}

// ---------------- sum 4 bf16 partials + SwiGLU -> act bf16 ----------------
__global__ __launch_bounds__(256) void swiglu_pass(
    const u16* __restrict__ gu_part, const int* __restrict__ n_slots,
    u16* __restrict__ act)
{
    int idx = blockIdx.x * 256 + threadIdx.x;
    int slot = idx >> 7;
    if (slot >= *n_slots) return;
    int i4 = (idx & 127) << 2;
    const u16* base = gu_part + (size_t)slot * TWO_I + i4;
    float g[4] = {0.f, 0.f, 0.f, 0.f}, u[4] = {0.f, 0.f, 0.f, 0.f};
#pragma unroll
    for (int k = 0; k < NSPL; ++k) {
        const u16* p = base + (size_t)k * SLOTS * TWO_I;
        ushort4 gv = *(const ushort4*)p;
        ushort4 uv = *(const ushort4*)(p + I_DIM);
        g[0] += bf2f(gv.x); g[1] += bf2f(gv.y); g[2] += bf2f(gv.z); g[3] += bf2f(gv.w);
        u[0] += bf2f(uv.x); u[1] += bf2f(uv.y); u[2] += bf2f(uv.z); u[3] += bf2f(uv.w);
    }
    float4 r;
    float* rp = &r.x;
#pragma unroll
    for (int j = 0; j < 4; ++j) {
        float gg = fminf(g[j], SWIGLU_LIMIT);
        float uu = fminf(fmaxf(u[j], -SWIGLU_LIMIT), SWIGLU_LIMIT);
        rp[j] = gg * (1.f / (1.f + __expf(-gg))) * uu;
    }
    *(ushort4*)(act + (size_t)slot * I_DIM + i4) = pack4(r);
}

// ---------------- GEMM2 (r5 inner structure, 64-row subtiles, XCD-pinned) ----------------
__global__ __launch_bounds__(256, 4) void gemm2_scatter(
    const u16* __restrict__ act, const float* __restrict__ w2,
    const int* __restrict__ A_tok, const float* __restrict__ A_w,
    const int* __restrict__ tile_e, const int* __restrict__ tile_r0,
    const int* __restrict__ jobs2, float* __restrict__ out)
{
    int b = blockIdx.x;
    int job = jobs2[(b & 7) * JCAP + (b >> 3)];
    if (job < 0) return;
    int y = job & 31;
    int tile2 = job >> 5;
    int e = tile_e[tile2 >> 1];
    int row0 = tile_r0[tile2 >> 1] + (tile2 & 1) * 64;
    int h0 = y * 64;
    int tid = threadIdx.x;

    __shared__ u16 As[2][4096];
    __shared__ u16 Bs[2][4096];

    const int l = tid & 63, w = tid >> 6;

    const int rlo = l >> 3;
    const int c8 = (l & 7) << 3;
    const int ksrc = c8 ^ (rlo << 3);
    const int rowA = w * 16 + rlo;
    const int rowB = rowA + 8;
    const u16* sAA = act + (size_t)(row0 + rowA) * I_DIM + ksrc;
    const u16* sAB = act + (size_t)(row0 + rowB) * I_DIM + ksrc;
    const int dA = w * 1024;

#define A_STAGE(bb, t) do { int ko = (t) * KC2; \
    gload16(sAA + ko, &As[bb][dA]);  gload16(sAB + ko, &As[bb][dA + 512]); } while (0)

    const int srow = tid >> 4;
    const int sc4  = tid & 15;
    const int kphys = (sc4 * 4) ^ ((srow & 7) << 3);
    const int sbase = srow * 64 + kphys;
    const float* bsrc = w2 + ((size_t)e * H_DIM + h0 + srow) * I_DIM + sc4 * 4;

    float4 bld[4];
#define B_LOAD(t) do { int k0 = (t) * KC2; \
    bld[0] = *(const float4*)(bsrc + k0); \
    bld[1] = *(const float4*)(bsrc + k0 + 16 * I_DIM); \
    bld[2] = *(const float4*)(bsrc + k0 + 32 * I_DIM); \
    bld[3] = *(const float4*)(bsrc + k0 + 48 * I_DIM); } while (0)

#define B_WRITE(bb) do { \
    *(ushort4*)&Bs[bb][sbase]        = pack4(bld[0]); \
    *(ushort4*)&Bs[bb][sbase + 1024] = pack4(bld[1]); \
    *(ushort4*)&Bs[bb][sbase + 2048] = pack4(bld[2]); \
    *(ushort4*)&Bs[bb][sbase + 3072] = pack4(bld[3]); } while (0)

    const int wm = w >> 1, wn = w & 1;
    const int lr = l & 15;
    const int lg = l >> 4;
    const int ra0 = wm * 32 + lr, ra1 = ra0 + 16;
    const int rb0 = wn * 32 + lr, rb1 = rb0 + 16;
    int ia0[2], ia1[2], ib0[2], ib1[2];
#pragma unroll
    for (int kh = 0; kh < 2; ++kh) {
        int e2 = kh * 32 + lg * 8;
        ia0[kh] = SWZ(ra0, e2); ia1[kh] = SWZ(ra1, e2);
        ib0[kh] = SWZ(rb0, e2); ib1[kh] = SWZ(rb1, e2);
    }

    const f32x4 Z4 = {0.f, 0.f, 0.f, 0.f};
    f32x4 acc[2][2];
#pragma unroll
    for (int m = 0; m < 2; ++m)
#pragma unroll
        for (int n = 0; n < 2; ++n) acc[m][n] = Z4;

    B_LOAD(0);
    A_STAGE(0, 0);
    B_WRITE(0);
    __syncthreads();
    int cur = 0;
    const int NT = I_DIM / KC2;            // 8
    for (int t = 0; t < NT; ++t) {
        const bool more = (t + 1 < NT);
        if (more) {
            A_STAGE(cur ^ 1, t + 1);
            B_LOAD(t + 1);
            SCHED0();
        }
#pragma unroll
        for (int kh = 0; kh < 2; ++kh) {
            bf16x8 a0 = *(const bf16x8*)&As[cur][ia0[kh]];
            bf16x8 a1 = *(const bf16x8*)&As[cur][ia1[kh]];
            bf16x8 b0 = *(const bf16x8*)&Bs[cur][ib0[kh]];
            bf16x8 b1 = *(const bf16x8*)&Bs[cur][ib1[kh]];
            acc[0][0] = __builtin_amdgcn_mfma_f32_16x16x32_bf16(a0, b0, acc[0][0], 0, 0, 0);
            acc[0][1] = __builtin_amdgcn_mfma_f32_16x16x32_bf16(a0, b1, acc[0][1], 0, 0, 0);
            acc[1][0] = __builtin_amdgcn_mfma_f32_16x16x32_bf16(a1, b0, acc[1][0], 0, 0, 0);
            acc[1][1] = __builtin_amdgcn_mfma_f32_16x16x32_bf16(a1, b1, acc[1][1], 0, 0, 0);
        }
        if (more) B_WRITE(cur ^ 1);
        __syncthreads();
        cur ^= 1;
    }
#undef A_STAGE
#undef B_LOAD
#undef B_WRITE

#pragma unroll
    for (int m = 0; m < 2; ++m)
#pragma unroll
        for (int n = 0; n < 2; ++n) {
            int col = h0 + wn * 32 + n * 16 + lr;
            int sb = wm * 32 + m * 16 + lg * 4;
#pragma unroll
            for (int q = 0; q < 4; ++q) {
                int slot = row0 + sb + q;
                int tok = A_tok[slot];
                if (tok >= 0)
                    atomicAdd(&out[(size_t)tok * H_DIM + col], acc[m][n][q] * A_w[slot]);
            }
        }
}

extern "C" void kernel_launch(void* const* d_in, const int* in_sizes, int n_in,
                              void* d_out, int out_size, void* d_ws, size_t ws_size,
                              hipStream_t stream) {
    const float* hs   = (const float*)d_in[0];
    const float* gw   = (const float*)d_in[1];
    const float* bias = (const float*)d_in[2];
    const float* w13  = (const float*)d_in[3];
    const float* w2   = (const float*)d_in[4];
    float* out = (float*)d_out;

    char* ws = (char*)d_ws;
    int*   cnt      = (int*)(ws + 0);          // 64 B
    int*   n_slots  = (int*)(ws + 64);         // 4 B
    int*   tile_e   = (int*)(ws + 128);        // 192 B
    int*   tile_r0  = (int*)(ws + 384);        // 192 B
    int*   jobs1    = (int*)(ws + 1024);       // 8*512*4 = 16384 -> 17408
    int*   jobs2    = (int*)(ws + 17408);      // 16384 -> 33792
    int*   tok_list = (int*)(ws + 33792);      // 131072 -> 164864
    float* w_list   = (float*)(ws + 164864);   // 131072 -> 295936
    int*   A_tok    = (int*)(ws + 295936);     // 24576  -> 320512
    float* A_w      = (float*)(ws + 320512);   // 24576  -> 345088
    u16*   act      = (u16*)(ws + 345088);     // 6291456 -> 6636544
    u16*   hs_bf    = (u16*)(ws + 6636544);    // 8388608 -> 15025152
    u16*   gu_part  = (u16*)(ws + 15025152);   // 4*6144*1024*2 = 50331648 -> ~65.4 MB

    hipMemsetAsync(d_out, 0, (size_t)T_TOK * H_DIM * sizeof(float), stream);
    hipMemsetAsync(cnt, 0, 64, stream);
    hipMemsetAsync(jobs1, 0xFF, 2 * 8 * JCAP * sizeof(int), stream);   // jobs1+jobs2 contiguous

    router_kernel<<<T_TOK / 2, 256, 0, stream>>>(hs, gw, bias, cnt, tok_list, w_list, hs_bf);
    scatter_build<<<(E_EXP * T_TOK) / 256, 256, 0, stream>>>(cnt, tok_list, w_list,
        A_tok, A_w, tile_e, tile_r0, n_slots, jobs1, jobs2);

    gemm1_gu<<<8 * JCAP, 256, 0, stream>>>(hs_bf, w13, A_tok, tile_e, tile_r0, jobs1, gu_part);
    swiglu_pass<<<SLOTS * I_DIM / 4 / 256, 256, 0, stream>>>(gu_part, n_slots, act);
    gemm2_scatter<<<8 * JCAP, 256, 0, stream>>>(act, w2, A_tok, A_w, tile_e, tile_r0, jobs2, out);
}

// Round 13
// 204.875 us; speedup vs baseline: 2.1208x; 2.1208x over previous
//
#include <hip/hip_runtime.h>
#include <hip/hip_bf16.h>
#include <math.h>

#define T_TOK 2048
#define H_DIM 2048
#define E_EXP 16
#define I_DIM 512
#define TWO_I 1024
#define ROUTED_SCALE 1.5f
#define SWIGLU_LIMIT 7.0f

#define BM 128            // gemm1 tile rows / A_tok padding
#define KC 32             // gemm1 K-chunk
#define KC2 64            // gemm2 K-chunk
#define MAX_TILES 48      // 128-row tiles
#define SLOTS 6144
#define NSPL 4            // gemm1 K-split
#define JCAP 512          // per-XCD job capacity

typedef __attribute__((ext_vector_type(8))) short bf16x8;
typedef __attribute__((ext_vector_type(4))) float f32x4;
typedef unsigned short u16;

__device__ inline u16 f2bf(float f) {
    return __builtin_bit_cast(u16, __float2bfloat16(f));
}
__device__ inline float bf2f(u16 h) {
    unsigned int u = ((unsigned int)h) << 16;
    return __builtin_bit_cast(float, u);
}
__device__ inline ushort4 pack4(float4 a) {
    ushort4 v;
    v.x = f2bf(a.x); v.y = f2bf(a.y); v.z = f2bf(a.z); v.w = f2bf(a.w);
    return v;
}
__device__ inline bf16x8 cvt8(float4 a, float4 b) {
    bf16x8 v;
    v[0] = (short)f2bf(a.x); v[1] = (short)f2bf(a.y);
    v[2] = (short)f2bf(a.z); v[3] = (short)f2bf(a.w);
    v[4] = (short)f2bf(b.x); v[5] = (short)f2bf(b.y);
    v[6] = (short)f2bf(b.z); v[7] = (short)f2bf(b.w);
    return v;
}

// async 16B/lane global->LDS DMA
__device__ inline void gload16(const u16* g, u16* l) {
    __builtin_amdgcn_global_load_lds(
        (const __attribute__((address_space(1))) void*)(g),
        (__attribute__((address_space(3))) void*)(l), 16, 0, 0);
}
#define SCHED0() __builtin_amdgcn_sched_barrier(0)

// swizzled ushort index for 64-elem bf16 rows
#define SWZ(row, k) ((row) * 64 + ((k) ^ (((row) & 7) << 3)))

// ---------------- router: TWO waves per token (H-split) ----------------
__global__ __launch_bounds__(256) void router_kernel(
    const float* __restrict__ hs, const float* __restrict__ gw,
    const float* __restrict__ bias, int* cnt, int* tok_list, float* w_list,
    u16* __restrict__ hs_bf)
{
    int w = threadIdx.x >> 6;
    int lane = threadIdx.x & 63;
    int t = blockIdx.x * 2 + (w >> 1);
    int kh = w & 1;
    const float* x = hs + (size_t)t * H_DIM + kh * 1024;
    const float* gwb = gw + kh * 1024;
    u16* hb = hs_bf + (size_t)t * H_DIM + kh * 1024;

    float acc[E_EXP];
#pragma unroll
    for (int e = 0; e < E_EXP; ++e) acc[e] = 0.f;

#pragma unroll
    for (int c = 0; c < 4; ++c) {
        int col = c * 256 + lane * 4;
        float4 xv = *(const float4*)(x + col);
        *(ushort4*)(hb + col) = pack4(xv);
#pragma unroll
        for (int e = 0; e < E_EXP; ++e) {
            float4 gv = *(const float4*)(gwb + (size_t)e * H_DIM + col);
            acc[e] = fmaf(xv.x, gv.x, acc[e]);
            acc[e] = fmaf(xv.y, gv.y, acc[e]);
            acc[e] = fmaf(xv.z, gv.z, acc[e]);
            acc[e] = fmaf(xv.w, gv.w, acc[e]);
        }
    }
#pragma unroll
    for (int e = 0; e < E_EXP; ++e) {
        for (int m = 32; m >= 1; m >>= 1)
            acc[e] += __shfl_xor(acc[e], m, 64);
    }
    __shared__ float part[4][E_EXP];
    if (lane == 0) {
#pragma unroll
        for (int e = 0; e < E_EXP; ++e) part[w][e] = acc[e];
    }
    __syncthreads();
    if (kh == 0 && lane == 0) {
        float sc[E_EXP], bsc[E_EXP];
#pragma unroll
        for (int e = 0; e < E_EXP; ++e) {
            float s = part[w][e] + part[w + 1][e];
            sc[e] = 1.f / (1.f + expf(-s));
            bsc[e] = sc[e] + bias[e];
        }
        int e0 = 0; float b0 = bsc[0];
#pragma unroll
        for (int e = 1; e < E_EXP; ++e) if (bsc[e] > b0) { b0 = bsc[e]; e0 = e; }
        int e1 = -1; float b1 = -1e30f;
#pragma unroll
        for (int e = 0; e < E_EXP; ++e) {
            if (e == e0) continue;
            if (bsc[e] > b1) { b1 = bsc[e]; e1 = e; }
        }
        float s0 = sc[e0], s1 = sc[e1];
        float inv = ROUTED_SCALE / (s0 + s1);
        int p0 = atomicAdd(&cnt[e0], 1);
        tok_list[e0 * T_TOK + p0] = t;
        w_list[e0 * T_TOK + p0] = s0 * inv;
        int p1 = atomicAdd(&cnt[e1], 1);
        tok_list[e1 * T_TOK + p1] = t;
        w_list[e1 * T_TOK + p1] = s1 * inv;
    }
}

// ---------------- parallel deterministic: compaction + tiles + XCD-pinned job lists ----------------
// jobs1[xcd*JCAP + i] = tile*32 + y*4 + kspl   (xcd = (e&1)*4 + kspl)
// jobs2[xcd*JCAP + i] = tile2*32 + y           (xcd = (e+y)&7; tile2 = 64-row subtile)
__global__ void scatter_build(const int* __restrict__ cnt,
    const int* __restrict__ tok_list, const float* __restrict__ w_list,
    int* A_tok, float* A_w, int* tile_e, int* tile_r0, int* n_slots,
    int* jobs1, int* jobs2)
{
    // tiny per-expert prefix sums, replicated in every thread
    int c[E_EXP], offs[E_EXP + 1], ptile[E_EXP + 1];
    offs[0] = 0; ptile[0] = 0;
#pragma unroll
    for (int e = 0; e < E_EXP; ++e) {
        c[e] = cnt[e];
        offs[e + 1] = offs[e] + ((c[e] + BM - 1) & ~(BM - 1));
        ptile[e + 1] = ptile[e] + ((c[e] + BM - 1) >> 7);
    }
    const int nt = ptile[E_EXP];

    int idx = blockIdx.x * 256 + threadIdx.x;

    // part 1: compaction with -1 padding
    {
        int e = idx >> 11;
        int pos = idx & (T_TOK - 1);
        int ce = c[e];
        int pe = (ce + BM - 1) & ~(BM - 1);
        if (pos < ce) {
            A_tok[offs[e] + pos] = tok_list[idx];
            A_w[offs[e] + pos] = w_list[idx];
        } else if (pos < pe) {
            A_tok[offs[e] + pos] = -1;
            A_w[offs[e] + pos] = 0.f;
        }
    }

    // part 2: tile descriptors + n_slots
    if (idx < MAX_TILES) {
        if (idx < nt) {
            int e = 0;
            while (ptile[e + 1] <= idx) ++e;
            tile_e[idx] = e;
            tile_r0[idx] = offs[e] + (idx - ptile[e]) * BM;
        } else {
            tile_e[idx] = -1;
        }
    }
    if (idx == 0) *n_slots = offs[E_EXP];

    // part 3: job lists, closed-form positions (deterministic, one thread per entry)
    if (idx < MAX_TILES * 96) {
        int t = idx / 96, r = idx % 96;
        if (t < nt) {
            int e = 0;
            while (ptile[e + 1] <= t) ++e;
            int g = e & 1;
            if (r < 32) {
                // jobs1: prior tiles with same expert-parity
                int oddPrior = 0;
#pragma unroll
                for (int e2 = 0; e2 < E_EXP; ++e2)
                    if ((e2 & 1) && e2 < e) oddPrior += ptile[e2 + 1] - ptile[e2];
                if (g) oddPrior += t - ptile[e];
                int samePrior = g ? oddPrior : (t - oddPrior);
                int kspl = r >> 3, y = r & 7;
                int x = g * 4 + kspl;
                jobs1[x * JCAP + samePrior * 8 + y] = t * 32 + y * 4 + kspl;
            } else {
                int j2 = r - 32;          // 0..63
                int s = j2 >> 5, yy = j2 & 31;
                int x = (e + yy) & 7;
                jobs2[x * JCAP + t * 8 + s * 4 + (yy >> 3)] = (t * 2 + s) * 32 + yy;
            }
        }
    }
}

// ---------------- GEMM1 (K-split x4, XCD-pinned): partial G/U -> gu_part bf16 ----------------
__global__ __launch_bounds__(256, 3) void gemm1_gu(
    const u16* __restrict__ hs_bf, const float* __restrict__ w13,
    const int* __restrict__ A_tok, const int* __restrict__ tile_e,
    const int* __restrict__ tile_r0, const int* __restrict__ jobs1,
    u16* __restrict__ gu_part)
{
    int b = blockIdx.x;
    int job = jobs1[(b & 7) * JCAP + (b >> 3)];
    if (job < 0) return;
    int kspl = job & 3;
    int y = (job >> 2) & 7;
    int tile = job >> 5;
    int e = tile_e[tile];
    int row0 = tile_r0[tile];
    int i0 = y * 64;
    int k0base = kspl * (H_DIM / NSPL);
    int tid = threadIdx.x;

    __shared__ u16 Xs[2][4096];
    __shared__ u16 Gs[2][2048];
    __shared__ u16 Us[2][2048];

    const int l = tid & 63, w = tid >> 6;

    const u16* sX[2]; int dX[2];
#pragma unroll
    for (int j = 0; j < 2; ++j) {
        int row = w * 32 + j * 16 + (l >> 2);
        int tk = A_tok[row0 + row]; if (tk < 0) tk = 0;
        int sg = (l & 3) ^ ((l >> 3) & 3);
        sX[j] = hs_bf + (size_t)tk * H_DIM + k0base + sg * 8;
        dX[j] = (w * 32 + j * 16) * 32;
    }
#define X_STAGE(bb, t) do { int ko = (t) * KC; \
    gload16(sX[0] + ko, &Xs[bb][dX[0]]); gload16(sX[1] + ko, &Xs[bb][dX[1]]); } while (0)

    const int wr = tid >> 2;
    const int wg = tid & 3;
    const int wsk = (wg ^ ((wr >> 1) & 3)) * 8;
    const float* gsrc = w13 + ((size_t)e * TWO_I + i0 + wr) * H_DIM + k0base + wsk;
    const float* usrc = gsrc + (size_t)I_DIM * H_DIM;
    const int wdst = wr * 32 + wg * 8;

    float4 gA, gB, uA, uB;
#define W_LOAD(t) do { int ko = (t) * KC; \
    gA = *(const float4*)(gsrc + ko); gB = *(const float4*)(gsrc + ko + 4); \
    uA = *(const float4*)(usrc + ko); uB = *(const float4*)(usrc + ko + 4); } while (0)
#define W_WRITE(bb) do { \
    *(bf16x8*)&Gs[bb][wdst] = cvt8(gA, gB); \
    *(bf16x8*)&Us[bb][wdst] = cvt8(uA, uB); } while (0)

    const int wm = w >> 1, wn = w & 1;
    const int lr = l & 15, lg = l >> 4;
    const int swz = (lg ^ ((lr >> 1) & 3)) * 8;
    int ix[4], ib[2];
#pragma unroll
    for (int m = 0; m < 4; ++m) ix[m] = (wm * 64 + m * 16 + lr) * 32 + swz;
#pragma unroll
    for (int n = 0; n < 2; ++n) ib[n] = (wn * 32 + n * 16 + lr) * 32 + swz;

    const f32x4 Z4 = {0.f, 0.f, 0.f, 0.f};
    f32x4 aG[4][2], aU[4][2];
#pragma unroll
    for (int m = 0; m < 4; ++m)
#pragma unroll
        for (int n = 0; n < 2; ++n) { aG[m][n] = Z4; aU[m][n] = Z4; }

    W_LOAD(0);
    X_STAGE(0, 0);
    W_WRITE(0);
    __syncthreads();
    int cur = 0;
    const int NT = (H_DIM / NSPL) / KC;     // 16
    for (int t = 0; t < NT; ++t) {
        const bool more = (t + 1 < NT);
        if (more) {
            X_STAGE(cur ^ 1, t + 1);
            W_LOAD(t + 1);
            SCHED0();
        }
        {
            bf16x8 a0 = *(const bf16x8*)&Xs[cur][ix[0]];
            bf16x8 a1 = *(const bf16x8*)&Xs[cur][ix[1]];
            bf16x8 a2 = *(const bf16x8*)&Xs[cur][ix[2]];
            bf16x8 a3 = *(const bf16x8*)&Xs[cur][ix[3]];
            bf16x8 g0 = *(const bf16x8*)&Gs[cur][ib[0]];
            bf16x8 g1 = *(const bf16x8*)&Gs[cur][ib[1]];
            bf16x8 u0 = *(const bf16x8*)&Us[cur][ib[0]];
            bf16x8 u1 = *(const bf16x8*)&Us[cur][ib[1]];
            aG[0][0] = __builtin_amdgcn_mfma_f32_16x16x32_bf16(a0, g0, aG[0][0], 0, 0, 0);
            aG[0][1] = __builtin_amdgcn_mfma_f32_16x16x32_bf16(a0, g1, aG[0][1], 0, 0, 0);
            aG[1][0] = __builtin_amdgcn_mfma_f32_16x16x32_bf16(a1, g0, aG[1][0], 0, 0, 0);
            aG[1][1] = __builtin_amdgcn_mfma_f32_16x16x32_bf16(a1, g1, aG[1][1], 0, 0, 0);
            aG[2][0] = __builtin_amdgcn_mfma_f32_16x16x32_bf16(a2, g0, aG[2][0], 0, 0, 0);
            aG[2][1] = __builtin_amdgcn_mfma_f32_16x16x32_bf16(a2, g1, aG[2][1], 0, 0, 0);
            aG[3][0] = __builtin_amdgcn_mfma_f32_16x16x32_bf16(a3, g0, aG[3][0], 0, 0, 0);
            aG[3][1] = __builtin_amdgcn_mfma_f32_16x16x32_bf16(a3, g1, aG[3][1], 0, 0, 0);
            aU[0][0] = __builtin_amdgcn_mfma_f32_16x16x32_bf16(a0, u0, aU[0][0], 0, 0, 0);
            aU[0][1] = __builtin_amdgcn_mfma_f32_16x16x32_bf16(a0, u1, aU[0][1], 0, 0, 0);
            aU[1][0] = __builtin_amdgcn_mfma_f32_16x16x32_bf16(a1, u0, aU[1][0], 0, 0, 0);
            aU[1][1] = __builtin_amdgcn_mfma_f32_16x16x32_bf16(a1, u1, aU[1][1], 0, 0, 0);
            aU[2][0] = __builtin_amdgcn_mfma_f32_16x16x32_bf16(a2, u0, aU[2][0], 0, 0, 0);
            aU[2][1] = __builtin_amdgcn_mfma_f32_16x16x32_bf16(a2, u1, aU[2][1], 0, 0, 0);
            aU[3][0] = __builtin_amdgcn_mfma_f32_16x16x32_bf16(a3, u0, aU[3][0], 0, 0, 0);
            aU[3][1] = __builtin_amdgcn_mfma_f32_16x16x32_bf16(a3, u1, aU[3][1], 0, 0, 0);
        }
        if (more) W_WRITE(cur ^ 1);
        __syncthreads();
        cur ^= 1;
    }
#undef X_STAGE
#undef W_LOAD
#undef W_WRITE

    u16* gp = gu_part + (size_t)kspl * SLOTS * TWO_I;
#pragma unroll
    for (int m = 0; m < 4; ++m)
#pragma unroll
        for (int n = 0; n < 2; ++n) {
            int col = i0 + wn * 32 + n * 16 + lr;
            int sbase = row0 + wm * 64 + m * 16 + lg * 4;
#pragma unroll
            for (int q = 0; q < 4; ++q) {
                gp[(size_t)(sbase + q) * TWO_I + col]         = f2bf(aG[m][n][q]);
                gp[(size_t)(sbase + q) * TWO_I + I_DIM + col] = f2bf(aU[m][n][q]);
            }
        }
}

// ---------------- sum 4 bf16 partials + SwiGLU -> act bf16 ----------------
__global__ __launch_bounds__(256) void swiglu_pass(
    const u16* __restrict__ gu_part, const int* __restrict__ n_slots,
    u16* __restrict__ act)
{
    int idx = blockIdx.x * 256 + threadIdx.x;
    int slot = idx >> 7;
    if (slot >= *n_slots) return;
    int i4 = (idx & 127) << 2;
    const u16* base = gu_part + (size_t)slot * TWO_I + i4;
    float g[4] = {0.f, 0.f, 0.f, 0.f}, u[4] = {0.f, 0.f, 0.f, 0.f};
#pragma unroll
    for (int k = 0; k < NSPL; ++k) {
        const u16* p = base + (size_t)k * SLOTS * TWO_I;
        ushort4 gv = *(const ushort4*)p;
        ushort4 uv = *(const ushort4*)(p + I_DIM);
        g[0] += bf2f(gv.x); g[1] += bf2f(gv.y); g[2] += bf2f(gv.z); g[3] += bf2f(gv.w);
        u[0] += bf2f(uv.x); u[1] += bf2f(uv.y); u[2] += bf2f(uv.z); u[3] += bf2f(uv.w);
    }
    float4 r;
    float* rp = &r.x;
#pragma unroll
    for (int j = 0; j < 4; ++j) {
        float gg = fminf(g[j], SWIGLU_LIMIT);
        float uu = fminf(fmaxf(u[j], -SWIGLU_LIMIT), SWIGLU_LIMIT);
        rp[j] = gg * (1.f / (1.f + __expf(-gg))) * uu;
    }
    *(ushort4*)(act + (size_t)slot * I_DIM + i4) = pack4(r);
}

// ---------------- GEMM2 (r5 inner structure, 64-row subtiles, XCD-pinned) ----------------
__global__ __launch_bounds__(256, 4) void gemm2_scatter(
    const u16* __restrict__ act, const float* __restrict__ w2,
    const int* __restrict__ A_tok, const float* __restrict__ A_w,
    const int* __restrict__ tile_e, const int* __restrict__ tile_r0,
    const int* __restrict__ jobs2, float* __restrict__ out)
{
    int b = blockIdx.x;
    int job = jobs2[(b & 7) * JCAP + (b >> 3)];
    if (job < 0) return;
    int y = job & 31;
    int tile2 = job >> 5;
    int e = tile_e[tile2 >> 1];
    int row0 = tile_r0[tile2 >> 1] + (tile2 & 1) * 64;
    int h0 = y * 64;
    int tid = threadIdx.x;

    __shared__ u16 As[2][4096];
    __shared__ u16 Bs[2][4096];

    const int l = tid & 63, w = tid >> 6;

    const int rlo = l >> 3;
    const int c8 = (l & 7) << 3;
    const int ksrc = c8 ^ (rlo << 3);
    const int rowA = w * 16 + rlo;
    const int rowB = rowA + 8;
    const u16* sAA = act + (size_t)(row0 + rowA) * I_DIM + ksrc;
    const u16* sAB = act + (size_t)(row0 + rowB) * I_DIM + ksrc;
    const int dA = w * 1024;

#define A_STAGE(bb, t) do { int ko = (t) * KC2; \
    gload16(sAA + ko, &As[bb][dA]);  gload16(sAB + ko, &As[bb][dA + 512]); } while (0)

    const int srow = tid >> 4;
    const int sc4  = tid & 15;
    const int kphys = (sc4 * 4) ^ ((srow & 7) << 3);
    const int sbase = srow * 64 + kphys;
    const float* bsrc = w2 + ((size_t)e * H_DIM + h0 + srow) * I_DIM + sc4 * 4;

    float4 bld[4];
#define B_LOAD(t) do { int k0 = (t) * KC2; \
    bld[0] = *(const float4*)(bsrc + k0); \
    bld[1] = *(const float4*)(bsrc + k0 + 16 * I_DIM); \
    bld[2] = *(const float4*)(bsrc + k0 + 32 * I_DIM); \
    bld[3] = *(const float4*)(bsrc + k0 + 48 * I_DIM); } while (0)

#define B_WRITE(bb) do { \
    *(ushort4*)&Bs[bb][sbase]        = pack4(bld[0]); \
    *(ushort4*)&Bs[bb][sbase + 1024] = pack4(bld[1]); \
    *(ushort4*)&Bs[bb][sbase + 2048] = pack4(bld[2]); \
    *(ushort4*)&Bs[bb][sbase + 3072] = pack4(bld[3]); } while (0)

    const int wm = w >> 1, wn = w & 1;
    const int lr = l & 15;
    const int lg = l >> 4;
    const int ra0 = wm * 32 + lr, ra1 = ra0 + 16;
    const int rb0 = wn * 32 + lr, rb1 = rb0 + 16;
    int ia0[2], ia1[2], ib0[2], ib1[2];
#pragma unroll
    for (int kh = 0; kh < 2; ++kh) {
        int e2 = kh * 32 + lg * 8;
        ia0[kh] = SWZ(ra0, e2); ia1[kh] = SWZ(ra1, e2);
        ib0[kh] = SWZ(rb0, e2); ib1[kh] = SWZ(rb1, e2);
    }

    const f32x4 Z4 = {0.f, 0.f, 0.f, 0.f};
    f32x4 acc[2][2];
#pragma unroll
    for (int m = 0; m < 2; ++m)
#pragma unroll
        for (int n = 0; n < 2; ++n) acc[m][n] = Z4;

    B_LOAD(0);
    A_STAGE(0, 0);
    B_WRITE(0);
    __syncthreads();
    int cur = 0;
    const int NT = I_DIM / KC2;            // 8
    for (int t = 0; t < NT; ++t) {
        const bool more = (t + 1 < NT);
        if (more) {
            A_STAGE(cur ^ 1, t + 1);
            B_LOAD(t + 1);
            SCHED0();
        }
#pragma unroll
        for (int kh = 0; kh < 2; ++kh) {
            bf16x8 a0 = *(const bf16x8*)&As[cur][ia0[kh]];
            bf16x8 a1 = *(const bf16x8*)&As[cur][ia1[kh]];
            bf16x8 b0 = *(const bf16x8*)&Bs[cur][ib0[kh]];
            bf16x8 b1 = *(const bf16x8*)&Bs[cur][ib1[kh]];
            acc[0][0] = __builtin_amdgcn_mfma_f32_16x16x32_bf16(a0, b0, acc[0][0], 0, 0, 0);
            acc[0][1] = __builtin_amdgcn_mfma_f32_16x16x32_bf16(a0, b1, acc[0][1], 0, 0, 0);
            acc[1][0] = __builtin_amdgcn_mfma_f32_16x16x32_bf16(a1, b0, acc[1][0], 0, 0, 0);
            acc[1][1] = __builtin_amdgcn_mfma_f32_16x16x32_bf16(a1, b1, acc[1][1], 0, 0, 0);
        }
        if (more) B_WRITE(cur ^ 1);
        __syncthreads();
        cur ^= 1;
    }
#undef A_STAGE
#undef B_LOAD
#undef B_WRITE

#pragma unroll
    for (int m = 0; m < 2; ++m)
#pragma unroll
        for (int n = 0; n < 2; ++n) {
            int col = h0 + wn * 32 + n * 16 + lr;
            int sb = wm * 32 + m * 16 + lg * 4;
#pragma unroll
            for (int q = 0; q < 4; ++q) {
                int slot = row0 + sb + q;
                int tok = A_tok[slot];
                if (tok >= 0)
                    atomicAdd(&out[(size_t)tok * H_DIM + col], acc[m][n][q] * A_w[slot]);
            }
        }
}

extern "C" void kernel_launch(void* const* d_in, const int* in_sizes, int n_in,
                              void* d_out, int out_size, void* d_ws, size_t ws_size,
                              hipStream_t stream) {
    const float* hs   = (const float*)d_in[0];
    const float* gw   = (const float*)d_in[1];
    const float* bias = (const float*)d_in[2];
    const float* w13  = (const float*)d_in[3];
    const float* w2   = (const float*)d_in[4];
    float* out = (float*)d_out;

    char* ws = (char*)d_ws;
    int*   cnt      = (int*)(ws + 0);          // 64 B
    int*   n_slots  = (int*)(ws + 64);         // 4 B
    int*   tile_e   = (int*)(ws + 128);        // 192 B
    int*   tile_r0  = (int*)(ws + 384);        // 192 B
    int*   jobs1    = (int*)(ws + 1024);       // 16384 -> 17408
    int*   jobs2    = (int*)(ws + 17408);      // 16384 -> 33792
    int*   tok_list = (int*)(ws + 33792);      // 131072 -> 164864
    float* w_list   = (float*)(ws + 164864);   // 131072 -> 295936
    int*   A_tok    = (int*)(ws + 295936);     // 24576  -> 320512
    float* A_w      = (float*)(ws + 320512);   // 24576  -> 345088
    u16*   act      = (u16*)(ws + 345088);     // 6291456 -> 6636544
    u16*   hs_bf    = (u16*)(ws + 6636544);    // 8388608 -> 15025152
    u16*   gu_part  = (u16*)(ws + 15025152);   // 4*6144*1024*2 -> ~65.4 MB

    hipMemsetAsync(d_out, 0, (size_t)T_TOK * H_DIM * sizeof(float), stream);
    hipMemsetAsync(cnt, 0, 64, stream);
    hipMemsetAsync(jobs1, 0xFF, 2 * 8 * JCAP * sizeof(int), stream);

    router_kernel<<<T_TOK / 2, 256, 0, stream>>>(hs, gw, bias, cnt, tok_list, w_list, hs_bf);
    scatter_build<<<(E_EXP * T_TOK) / 256, 256, 0, stream>>>(cnt, tok_list, w_list,
        A_tok, A_w, tile_e, tile_r0, n_slots, jobs1, jobs2);

    gemm1_gu<<<8 * JCAP, 256, 0, stream>>>(hs_bf, w13, A_tok, tile_e, tile_r0, jobs1, gu_part);
    swiglu_pass<<<SLOTS * I_DIM / 4 / 256, 256, 0, stream>>>(gu_part, n_slots, act);
    gemm2_scatter<<<8 * JCAP, 256, 0, stream>>>(act, w2, A_tok, A_w, tile_e, tile_r0, jobs2, out);
}